// Round 5
// baseline (100.948 us; speedup 1.0000x reference)
//
#include <hip/hip_runtime.h>

#define NXS   65536
#define HID   32
#define BT    512            // 8 waves per block
#define NB    256            // blocks = CUs
#define OWN   256            // cells written per block
#define HOLD  1024           // cells held per block (2 per lane)
#define HALO  ((HOLD - OWN) / 2)   // 384 >= 200 steps -> single launch
#define LUT_N 4096
#define LUT_INV  512.0f      // entries per unit c, range [-4,4)
#define LUT_BIAS 2048.0f     // 4 * 512

__device__ __forceinline__ float fexp2(float x) { return __builtin_amdgcn_exp2f(x); }
__device__ __forceinline__ float frcp(float x)  { return __builtin_amdgcn_rcpf(x); }
__device__ __forceinline__ float flog2(float x) { return __builtin_amdgcn_logf(x); }

__device__ __forceinline__ float fast_tanh(float x) {
    x = fminf(fmaxf(x, -15.0f), 15.0f);
    float e = fexp2(x * 2.8853900817779268f);   // e^{2x}
    return (e - 1.0f) * frcp(e + 1.0f);
}
__device__ __forceinline__ float fast_sigmoid(float x) {
    float e = fexp2(x * -1.4426950408889634f);
    return frcp(1.0f + e);
}

struct FinnPtrs {
    const float* tvec;
    const float* Dp;  const float* stencil; const float* BCp; const float* fp;
    const float* kdp; const float* betap;   const float* alphap; const float* rhosp;
    const float* nep; const float* vep;     const float* dxp;
};

// ---- Kernel 1: tabulate (ret(c), clip(c)^beta) on [-4,4) as float2 ----
__global__ __launch_bounds__(256) void finn_lut(
    const float* __restrict__ W0, const float* __restrict__ b0,
    const float* __restrict__ W1, const float* __restrict__ b1,
    const float* __restrict__ W2, const float* __restrict__ b2,
    const float* __restrict__ W3, const float* __restrict__ b3,
    const float* __restrict__ ret_fac, const float* __restrict__ betap,
    float2* __restrict__ lut)
{
    const int i = blockIdx.x * 256 + threadIdx.x;
    if (i >= LUT_N) return;
    const float c = -4.0f + (float)i * (1.0f / LUT_INV);

    float h[HID], a[HID];
    #pragma unroll
    for (int j = 0; j < HID; ++j)
        h[j] = fast_tanh(fmaf(c, W0[j], b0[j]));

    #pragma unroll
    for (int j = 0; j < HID; ++j) a[j] = b1[j];
    #pragma unroll
    for (int k = 0; k < HID; ++k) {
        const float hk = h[k];
        #pragma unroll
        for (int j = 0; j < HID; ++j) a[j] = fmaf(hk, W1[k * HID + j], a[j]);
    }
    #pragma unroll
    for (int j = 0; j < HID; ++j) h[j] = fast_tanh(a[j]);

    #pragma unroll
    for (int j = 0; j < HID; ++j) a[j] = b2[j];
    #pragma unroll
    for (int k = 0; k < HID; ++k) {
        const float hk = h[k];
        #pragma unroll
        for (int j = 0; j < HID; ++j) a[j] = fmaf(hk, W2[k * HID + j], a[j]);
    }
    #pragma unroll
    for (int j = 0; j < HID; ++j) h[j] = fast_tanh(a[j]);

    float pre = b3[0];
    #pragma unroll
    for (int k = 0; k < HID; ++k) pre = fmaf(h[k], W3[k], pre);

    const float ret = fast_sigmoid(pre) * ret_fac[0];
    const float cc  = fmaxf(c, 1e-9f);
    const float pw  = fexp2(betap[0] * flog2(cc));   // clip(c,1e-9)^beta
    lut[i] = make_float2(ret, pw);
}

// ---- Kernel 2: 2-cells/lane sweep, single launch, paired-float4 LUT ----
__global__ __launch_bounds__(BT) void finn_sweep(
    const float* __restrict__ uin, float* __restrict__ out,
    const float2* __restrict__ lut_g, FinnPtrs P, int t0, int h)
{
    __shared__ float4 slut[LUT_N];        // 64 KB: (ret_i,pow_i,ret_{i+1},pow_{i+1})
    __shared__ float  sA[2][10];          // left-edge feed:  wave w reads sA[p][w]
    __shared__ float  sB[2][10];          // right-edge feed: wave w reads sB[p][w]

    const int tid = threadIdx.x;
    const int b   = blockIdx.x;

    // stage paired LUT (8 iters; one-time)
    #pragma unroll
    for (int j = 0; j < LUT_N / BT; ++j) {
        const int i = tid + j * BT;
        const float2 l0 = lut_g[i];
        const float2 l1 = lut_g[(i + 1 < LUT_N) ? (i + 1) : i];
        slut[i] = make_float4(l0.x, l0.y, l1.x, l1.y);
    }

    // wave-uniform scalars
    const float dt   = P.tvec[1] - P.tvec[0];
    const float s0   = P.stencil[0];
    const float s1   = P.stencil[1];
    const float dx   = P.dxp[0];
    const float Ddx2 = P.Dp[0] / (dx * dx);
    const float vedx = P.vep[0] / dx;
    const float BC   = P.BCp[0];
    const float alp  = P.alphap[0];
    const float akd  = (1.0f - P.fp[0]) * P.kdp[0];
    const float rsne = P.rhosp[0] / P.nep[0];

    // geometry: block owns [b*OWN, b*OWN+OWN); holds base .. base+HOLD
    int base = b * OWN - HALO;
    if (base < 0) base = 0;
    if (base > NXS - HOLD) base = NXS - HOLD;
    const int gi0   = base + 2 * tid;     // even
    const int ownLo = b * OWN;
    const bool ownm = (gi0 >= ownLo) && (gi0 < ownLo + OWN);
    const bool isF0 = (gi0 == 0);
    const bool isL1 = (gi0 + 1 == NXS - 1);
    const int  w    = tid >> 6;
    const int  lane = tid & 63;
    const int  slotB = (w + 9) % 10;      // w==0 -> dummy slot 9, else w-1

    float c0, sk0, c1, sk1;
    {
        const float4 u = reinterpret_cast<const float4*>(uin)[base / 2 + tid];
        c0 = u.x; sk0 = u.y; c1 = u.z; sk1 = u.w;
    }

    __syncthreads();   // LUT staged

    float* __restrict__ orow = out + (size_t)t0 * NXS * 2 + 2 * gi0;

    int p = 0;
    for (int s = 0; s < h; ++s) {
        // publish wave-edge cells; intra-wave edge neighbors via shfl
        if (lane == 63) sA[p][w + 1] = c1;
        if (lane == 0)  sB[p][slotB] = c0;
        const float clS = __shfl_up(c1, 1);     // left nbr of cell0
        const float crS = __shfl_down(c0, 1);   // right nbr of cell1

        asm volatile("s_waitcnt lgkmcnt(0)" ::: "memory");
        __builtin_amdgcn_s_barrier();
        asm volatile("" ::: "memory");

        // LUT gathers first (latency overlapped by stencil VALU below)
        float tt0 = fmaf(c0, LUT_INV, LUT_BIAS);
        tt0 = fminf(fmaxf(tt0, 0.0f), (float)(LUT_N - 1) - 0.001f);
        const int   i0 = (int)tt0;
        const float fr0 = tt0 - (float)i0;
        const float4 L0 = slut[i0];

        float tt1 = fmaf(c1, LUT_INV, LUT_BIAS);
        tt1 = fminf(fmaxf(tt1, 0.0f), (float)(LUT_N - 1) - 0.001f);
        const int   i1 = (int)tt1;
        const float fr1 = tt1 - (float)i1;
        const float4 L1 = slut[i1];

        const float eA = sA[p][w];
        const float eB = sB[p][w];

        float cl0 = (lane == 0)  ? eA : clS;
        cl0 = isF0 ? BC : cl0;
        const float cr0 = c1;
        const float cl1 = c0;
        float cr1 = (lane == 63) ? eB : crS;
        cr1 = isL1 ? c1 : cr1;

        // ---- cell 0 ----
        {
            const float ret  = fmaf(fr0, L0.z - L0.x, L0.x);
            const float powc = fmaf(fr0, L0.w - L0.y, L0.y);
            float lf = fmaf(s1, cl0, s0 * c0);
            if (isF0) lf *= 2.0f;
            const float rff  = fmaf(s1, cr0, s0 * c0);
            const float diff = Ddx2 * (lf + rff);
            const float adv  = vedx * (c0 - cl0);
            const float dsk  = alp * fmaf(akd, powc, -sk0);
            const float dc   = fmaf(ret, diff - adv, -rsne * dsk);
            c0  = fmaf(dt, dc,  c0);
            sk0 = fmaf(dt, dsk, sk0);
        }
        // ---- cell 1 ----
        {
            const float ret  = fmaf(fr1, L1.z - L1.x, L1.x);
            const float powc = fmaf(fr1, L1.w - L1.y, L1.y);
            const float lf   = fmaf(s1, cl1, s0 * c1);
            const float rff  = fmaf(s1, cr1, s0 * c1);
            const float diff = Ddx2 * (lf + rff);
            const float adv  = vedx * (c1 - cl1);
            const float dsk  = alp * fmaf(akd, powc, -sk1);
            const float dc   = fmaf(ret, diff - adv, -rsne * dsk);
            c1  = fmaf(dt, dc,  c1);
            sk1 = fmaf(dt, dsk, sk1);
        }

        if (ownm)
            *reinterpret_cast<float4*>(orow) = make_float4(c0, sk0, c1, sk1);
        orow += NXS * 2;
        p ^= 1;
    }
}

extern "C" void kernel_launch(void* const* d_in, const int* in_sizes, int n_in,
                              void* d_out, int out_size, void* d_ws, size_t ws_size,
                              hipStream_t stream)
{
    const float* u0 = (const float*)d_in[0];
    FinnPtrs P;
    P.tvec    = (const float*)d_in[1];
    const float* W0      = (const float*)d_in[2];
    const float* b0      = (const float*)d_in[3];
    const float* W1      = (const float*)d_in[4];
    const float* b1      = (const float*)d_in[5];
    const float* W2      = (const float*)d_in[6];
    const float* b2      = (const float*)d_in[7];
    const float* W3      = (const float*)d_in[8];
    const float* b3      = (const float*)d_in[9];
    const float* ret_fac = (const float*)d_in[10];
    P.Dp      = (const float*)d_in[11];
    P.stencil = (const float*)d_in[12];
    P.BCp     = (const float*)d_in[13];
    P.fp      = (const float*)d_in[14];
    P.kdp     = (const float*)d_in[15];
    P.betap   = (const float*)d_in[16];
    P.alphap  = (const float*)d_in[17];
    P.rhosp   = (const float*)d_in[18];
    P.nep     = (const float*)d_in[19];
    P.vep     = (const float*)d_in[20];
    P.dxp     = (const float*)d_in[21];

    float* out = (float*)d_out;
    float2* lut = (float2*)d_ws;        // 32 KB scratch
    const int T = in_sizes[1];          // 200

    hipLaunchKernelGGL(finn_lut, dim3(LUT_N / 256), dim3(256), 0, stream,
                       W0, b0, W1, b1, W2, b2, W3, b3, ret_fac, P.betap, lut);

    int done = 0;
    while (done < T) {
        const int h = (T - done < HALO) ? (T - done) : HALO;   // T=200 -> one launch
        const float* src = (done == 0) ? u0 : out + (size_t)(done - 1) * NXS * 2;
        hipLaunchKernelGGL(finn_sweep, dim3(NB), dim3(BT), 0, stream,
                           src, out, lut, P, done, h);
        done += h;
    }
}

// Round 6
// 84.899 us; speedup vs baseline: 1.1890x; 1.1890x over previous
//
#include <hip/hip_runtime.h>

#define NXS   65536
#define HID   32
#define BT    512            // 8 waves per block
#define NB    256            // blocks = CUs
#define OWN   256            // cells written per block
#define HOLD  1024           // cells held per block (2 per lane)
#define HALO  ((HOLD - OWN) / 2)   // 384 >= 200 steps -> single launch
#define LUT_N 4096
#define LUT_INV  512.0f      // entries per unit c, range [-4,4)
#define LUT_BIAS 2048.0f     // 4 * 512

__device__ __forceinline__ float fexp2(float x) { return __builtin_amdgcn_exp2f(x); }
__device__ __forceinline__ float frcp(float x)  { return __builtin_amdgcn_rcpf(x); }
__device__ __forceinline__ float flog2(float x) { return __builtin_amdgcn_logf(x); }

__device__ __forceinline__ float fast_tanh(float x) {
    x = fminf(fmaxf(x, -15.0f), 15.0f);
    float e = fexp2(x * 2.8853900817779268f);   // e^{2x}
    return (e - 1.0f) * frcp(e + 1.0f);
}
__device__ __forceinline__ float fast_sigmoid(float x) {
    float e = fexp2(x * -1.4426950408889634f);
    return frcp(1.0f + e);
}

struct FinnPtrs {
    const float* tvec;
    const float* Dp;  const float* stencil; const float* BCp; const float* fp;
    const float* kdp; const float* betap;   const float* alphap; const float* rhosp;
    const float* nep; const float* vep;     const float* dxp;
};

// ---- Kernel 1: tabulate ret(c) = sigmoid(MLP(c)) * ret_fac on [-4,4) ----
__global__ __launch_bounds__(256) void finn_lut(
    const float* __restrict__ W0, const float* __restrict__ b0,
    const float* __restrict__ W1, const float* __restrict__ b1,
    const float* __restrict__ W2, const float* __restrict__ b2,
    const float* __restrict__ W3, const float* __restrict__ b3,
    const float* __restrict__ ret_fac, float* __restrict__ lut)
{
    const int i = blockIdx.x * 256 + threadIdx.x;
    if (i >= LUT_N) return;
    const float c = -4.0f + (float)i * (1.0f / LUT_INV);

    float h[HID], a[HID];
    #pragma unroll
    for (int j = 0; j < HID; ++j)
        h[j] = fast_tanh(fmaf(c, W0[j], b0[j]));

    #pragma unroll
    for (int j = 0; j < HID; ++j) a[j] = b1[j];
    #pragma unroll
    for (int k = 0; k < HID; ++k) {
        const float hk = h[k];
        #pragma unroll
        for (int j = 0; j < HID; ++j) a[j] = fmaf(hk, W1[k * HID + j], a[j]);
    }
    #pragma unroll
    for (int j = 0; j < HID; ++j) h[j] = fast_tanh(a[j]);

    #pragma unroll
    for (int j = 0; j < HID; ++j) a[j] = b2[j];
    #pragma unroll
    for (int k = 0; k < HID; ++k) {
        const float hk = h[k];
        #pragma unroll
        for (int j = 0; j < HID; ++j) a[j] = fmaf(hk, W2[k * HID + j], a[j]);
    }
    #pragma unroll
    for (int j = 0; j < HID; ++j) h[j] = fast_tanh(a[j]);

    float pre = b3[0];
    #pragma unroll
    for (int k = 0; k < HID; ++k) pre = fmaf(h[k], W3[k], pre);

    lut[i] = fast_sigmoid(pre) * ret_fac[0];
}

// ---- Kernel 2: 2 cells/lane, folded constants, b64 LUT, pipelined gathers ----
__global__ __launch_bounds__(BT) void finn_sweep(
    const float* __restrict__ uin, float* __restrict__ out,
    const float* __restrict__ lut_g, FinnPtrs P, int t0, int h)
{
    __shared__ float2 slut[LUT_N];   // (ret_i, ret_{i+1}) pairs, 32 KB
    __shared__ float2 sE[2][10];     // edge exchange, parity-buffered

    const int tid = threadIdx.x;
    const int b   = blockIdx.x;

    // stage paired LUT (8 iters, one-time)
    #pragma unroll
    for (int j = 0; j < LUT_N / BT; ++j) {
        const int i = tid + j * BT;
        const float r0 = lut_g[i];
        const float r1 = lut_g[(i + 1 < LUT_N) ? (i + 1) : i];
        slut[i] = make_float2(r0, r1);
    }
    if (tid < 40) reinterpret_cast<float*>(sE)[tid] = 0.0f;

    // wave-uniform scalars
    const float dt   = P.tvec[1] - P.tvec[0];
    const float s0   = P.stencil[0];
    const float s1   = P.stencil[1];
    const float dx   = P.dxp[0];
    const float A    = P.Dp[0] / (dx * dx);     // Ddx2
    const float B    = P.vep[0] / dx;           // vedx
    const float BC   = P.BCp[0];
    const float beta = P.betap[0];
    const float alp  = P.alphap[0];
    const float akd  = (1.0f - P.fp[0]) * P.kdp[0];
    const float rsne = P.rhosp[0] / P.nep[0];

    const float G    = dt * rsne * alp;
    const float GAKD = G * akd;
    const float S1c  = 1.0f - dt * alp;
    const float S2c  = dt * alp * akd;

    // geometry
    int base = b * OWN - HALO;
    if (base < 0) base = 0;
    if (base > NXS - HOLD) base = NXS - HOLD;
    const int gi0   = base + 2 * tid;
    const int ownLo = b * OWN;
    const bool ownm = (gi0 >= ownLo) && (gi0 < ownLo + OWN);
    const bool isF0 = (gi0 == 0);
    const bool isL1 = (gi0 + 1 == NXS - 1);
    const int  w    = tid >> 6;
    const int  lane = tid & 63;

    // per-lane folded update constants (all boundary logic absorbed here)
    const float K0_0 = isF0 ? dt * (2.0f * A * s1 + B) * BC : 0.0f;
    const float K1_0 = dt * (isF0 ? (3.0f * A * s0 - B) : (2.0f * A * s0 - B));
    const float K2_0 = isF0 ? 0.0f : dt * (A * s1 + B);
    const float K3_0 = dt * A * s1;
    const float K1_1 = dt * (2.0f * A * s0 - B) + (isL1 ? dt * A * s1 : 0.0f);
    const float K2_1 = dt * (A * s1 + B);
    const float K3_1 = isL1 ? 0.0f : dt * A * s1;

    float c0, sk0, c1, sk1;
    {
        const float4 u = reinterpret_cast<const float4*>(uin)[base / 2 + tid];
        c0 = u.x; sk0 = u.y; c1 = u.z; sk1 = u.w;
    }

    __syncthreads();   // LUT + sE init visible

    // prologue gathers for step 0
    int i0, i1; float fr0, fr1;
    {
        float tt0 = fmaf(c0, LUT_INV, LUT_BIAS);
        tt0 = fminf(fmaxf(tt0, 0.0f), (float)(LUT_N - 1) - 0.001f);
        i0 = (int)tt0; fr0 = tt0 - (float)i0;
        float tt1 = fmaf(c1, LUT_INV, LUT_BIAS);
        tt1 = fminf(fmaxf(tt1, 0.0f), (float)(LUT_N - 1) - 0.001f);
        i1 = (int)tt1; fr1 = tt1 - (float)i1;
    }
    float2 L0 = slut[i0];
    float2 L1 = slut[i1];

    float* __restrict__ orow = out + (size_t)t0 * NXS * 2 + 2 * gi0;

    int p = 0;
    for (int s = 0; s < h; ++s) {
        // publish edge cells: one ds_write_b32, lanes 0 & 63 active
        {
            float* ea = nullptr; float ev = 0.0f;
            if (lane == 63) { ea = &sE[p][w + 2].x; ev = c1; }
            if (lane == 0)  { ea = &sE[p][w].y;     ev = c0; }
            if (ea) *ea = ev;
        }
        const float clS = __shfl_up(c1, 1);     // left nbr of cell0
        const float crS = __shfl_down(c0, 1);   // right nbr of cell1

        // own-cell VALU (overlaps LDS latency)
        const float pw0  = fexp2(beta * flog2(fmaxf(c0, 1e-9f)));   // c^beta exact
        const float pw1  = fexp2(beta * flog2(fmaxf(c1, 1e-9f)));
        const float ret0 = fmaf(fr0, L0.y - L0.x, L0.x);
        const float ret1 = fmaf(fr1, L1.y - L1.x, L1.x);
        const float nsk0 = fmaf(S1c, sk0, S2c * pw0);
        const float nsk1 = fmaf(S1c, sk1, S2c * pw1);
        float t0 = fmaf(K1_0, c0, K0_0);
        float t1 = fmaf(K1_1, c1, 0.0f);

        asm volatile("s_waitcnt lgkmcnt(0)" ::: "memory");
        __builtin_amdgcn_s_barrier();
        asm volatile("" ::: "memory");

        const float2 e = sE[p][w + 1];          // wave-uniform b64 broadcast

        const float cl0 = (lane == 0)  ? e.x : clS;
        const float cr1 = (lane == 63) ? e.y : crS;

        t0 = fmaf(K2_0, cl0, t0); t0 = fmaf(K3_0, c1, t0);     // cr0 = c1 (old)
        t1 = fmaf(K2_1, c0, t1);  t1 = fmaf(K3_1, cr1, t1);    // cl1 = c0 (old)
        float nc0 = fmaf(ret0, t0, c0);
        nc0 = fmaf(-GAKD, pw0, nc0);
        nc0 = fmaf(G, sk0, nc0);
        float nc1 = fmaf(ret1, t1, c1);
        nc1 = fmaf(-GAKD, pw1, nc1);
        nc1 = fmaf(G, sk1, nc1);

        c0 = nc0; c1 = nc1; sk0 = nsk0; sk1 = nsk1;

        // issue next-step gathers early (latency hidden under next pre-barrier zone)
        {
            float tt0 = fmaf(c0, LUT_INV, LUT_BIAS);
            tt0 = fminf(fmaxf(tt0, 0.0f), (float)(LUT_N - 1) - 0.001f);
            i0 = (int)tt0; fr0 = tt0 - (float)i0;
            float tt1 = fmaf(c1, LUT_INV, LUT_BIAS);
            tt1 = fminf(fmaxf(tt1, 0.0f), (float)(LUT_N - 1) - 0.001f);
            i1 = (int)tt1; fr1 = tt1 - (float)i1;
        }
        L0 = slut[i0];
        L1 = slut[i1];

        if (ownm)
            *reinterpret_cast<float4*>(orow) = make_float4(c0, sk0, c1, sk1);
        orow += NXS * 2;
        p ^= 1;
    }
}

extern "C" void kernel_launch(void* const* d_in, const int* in_sizes, int n_in,
                              void* d_out, int out_size, void* d_ws, size_t ws_size,
                              hipStream_t stream)
{
    const float* u0 = (const float*)d_in[0];
    FinnPtrs P;
    P.tvec    = (const float*)d_in[1];
    const float* W0      = (const float*)d_in[2];
    const float* b0      = (const float*)d_in[3];
    const float* W1      = (const float*)d_in[4];
    const float* b1      = (const float*)d_in[5];
    const float* W2      = (const float*)d_in[6];
    const float* b2      = (const float*)d_in[7];
    const float* W3      = (const float*)d_in[8];
    const float* b3      = (const float*)d_in[9];
    const float* ret_fac = (const float*)d_in[10];
    P.Dp      = (const float*)d_in[11];
    P.stencil = (const float*)d_in[12];
    P.BCp     = (const float*)d_in[13];
    P.fp      = (const float*)d_in[14];
    P.kdp     = (const float*)d_in[15];
    P.betap   = (const float*)d_in[16];
    P.alphap  = (const float*)d_in[17];
    P.rhosp   = (const float*)d_in[18];
    P.nep     = (const float*)d_in[19];
    P.vep     = (const float*)d_in[20];
    P.dxp     = (const float*)d_in[21];

    float* out = (float*)d_out;
    float* lut = (float*)d_ws;          // 16 KB scratch
    const int T = in_sizes[1];          // 200

    hipLaunchKernelGGL(finn_lut, dim3(LUT_N / 256), dim3(256), 0, stream,
                       W0, b0, W1, b1, W2, b2, W3, b3, ret_fac, lut);

    int done = 0;
    while (done < T) {
        const int h = (T - done < HALO) ? (T - done) : HALO;   // T=200 -> one launch
        const float* src = (done == 0) ? u0 : out + (size_t)(done - 1) * NXS * 2;
        hipLaunchKernelGGL(finn_sweep, dim3(NB), dim3(BT), 0, stream,
                           src, out, lut, P, done, h);
        done += h;
    }
}